// Round 2
// baseline (278.492 us; speedup 1.0000x reference)
//
#include <hip/hip_runtime.h>

#define NFEAT 38

typedef __attribute__((ext_vector_type(8))) short bf16x8;
typedef __attribute__((ext_vector_type(4))) float f32x4;

__device__ __forceinline__ float4 ld4(const float* p) {
    return *reinterpret_cast<const float4*>(p);
}
__device__ __forceinline__ void add4(float4& a, float4 b) {
    a.x += b.x; a.y += b.y; a.z += b.z; a.w += b.w;
}
__device__ __forceinline__ unsigned short f2bf(float f) {
    unsigned int u = __float_as_uint(f);
    u += 0x7fffu + ((u >> 16) & 1u);   // round-to-nearest-even
    return (unsigned short)(u >> 16);
}

// ---------------------------------------------------------------------------
// K0a: fused[r][c], r in [0,896):
//   r<512   : species_tbl[r]  @ agg_w[0:512]   + species_emb[r] + agg_b
//   512..639: ability_tbl[r'] @ agg_w[512:640] + ability_emb[r']
//   640..895: item_tbl[r']    @ agg_w[640:896] + item_emb[r']
// ---------------------------------------------------------------------------
__global__ __launch_bounds__(256) void k_fused(
    const float* __restrict__ sp_tbl, const float* __restrict__ ab_tbl,
    const float* __restrict__ it_tbl, const float* __restrict__ sp_emb,
    const float* __restrict__ ab_emb, const float* __restrict__ it_emb,
    const float* __restrict__ agg_w,  const float* __restrict__ agg_b,
    float* __restrict__ fused)
{
    __shared__ float row[512];
    int r = blockIdx.x, c = threadIdx.x;
    const float* src; const float* emb; int len, wbase; float acc;
    if (r < 512)      { src = sp_tbl + r * 512;         emb = sp_emb + r * 256;         len = 512; wbase = 0;   acc = agg_b[c]; }
    else if (r < 640) { int q = r - 512; src = ab_tbl + q * 128; emb = ab_emb + q * 256; len = 128; wbase = 512; acc = 0.f; }
    else              { int q = r - 640; src = it_tbl + q * 256; emb = it_emb + q * 256; len = 256; wbase = 640; acc = 0.f; }
    for (int i = c; i < len; i += 256) row[i] = src[i];
    __syncthreads();
    acc += emb[c];
    for (int k = 0; k < len; ++k)
        acc += row[k] * agg_w[(wbase + k) * 256 + c];
    fused[r * 256 + c] = acc;
}

// ---------------------------------------------------------------------------
// K0b: wbt[c][k] = bf16(mlp_w[k][c])  (transposed bf16 copy for MFMA B-frags)
// ---------------------------------------------------------------------------
__global__ __launch_bounds__(256) void k_wbt(
    const float* __restrict__ mlp_w, unsigned short* __restrict__ wbt)
{
    int c = blockIdx.x, k = threadIdx.x;
    wbt[c * 256 + k] = f2bf(mlp_w[k * 256 + c]);
}

// ---------------------------------------------------------------------------
// K0c: byte tables for the 11 bits16 features (feats 23..33).
//   t = 2*fi + half (fi in 0..10), b in 0..255:
//   btbl[(t*256+b)][c] = sum_{j<8, bit j of b set} agg_w[1171 + 16*fi + 8*half + j][c]
// ---------------------------------------------------------------------------
__global__ __launch_bounds__(256) void k_btbl(
    const float* __restrict__ agg_w, float* __restrict__ btbl)
{
    int t = blockIdx.x >> 8;    // 0..21
    int b = blockIdx.x & 255;
    int c = threadIdx.x;
    int base = 1171 + 16 * (t >> 1) + 8 * (t & 1);
    float acc = 0.f;
    #pragma unroll
    for (int j = 0; j < 8; ++j)
        if ((b >> j) & 1) acc += agg_w[(base + j) * 256 + c];
    btbl[(size_t)blockIdx.x * 256 + c] = acc;
}

// ---------------------------------------------------------------------------
// K1: per-entity gather-sum -> relu -> bf16 xr.  One wave per entity,
// lane handles 4 consecutive output cols (float4).
// ---------------------------------------------------------------------------
__global__ __launch_bounds__(256) void k_encode(
    const int* __restrict__ ent, const float* __restrict__ fused,
    const float* __restrict__ btbl, const float* __restrict__ agg_w,
    const float* __restrict__ actions_emb, unsigned short* __restrict__ xr)
{
    int e    = (blockIdx.x << 2) + (threadIdx.x >> 6);
    int lane = threadIdx.x & 63;
    int c0   = lane << 2;
    const int* f = ent + (size_t)e * NFEAT;

    float4 acc = ld4(fused + (size_t)f[0] * 256 + c0);           // species (incl emb + agg_b)
    add4(acc, ld4(fused + (size_t)(512 + f[1]) * 256 + c0));     // ability
    add4(acc, ld4(fused + (size_t)(640 + f[2]) * 256 + c0));     // item

    const int offs[13] = {896, 997, 999, 1001, 1033, 1036, 1044,
                          1060, 1062, 1064, 1066, 1074, 1078};
    #pragma unroll
    for (int i = 0; i < 13; ++i)
        add4(acc, ld4(agg_w + (size_t)(offs[i] + f[3 + i]) * 256 + c0));
    #pragma unroll
    for (int i = 0; i < 7; ++i)
        add4(acc, ld4(agg_w + (size_t)(1080 + 13 * i + f[16 + i]) * 256 + c0));
    #pragma unroll
    for (int i = 0; i < 11; ++i) {
        int v = f[23 + i];
        add4(acc, ld4(btbl + ((size_t)(i * 512) + (v & 255)) * 256 + c0));
        add4(acc, ld4(btbl + ((size_t)(i * 512) + 256 + ((v >> 8) & 255)) * 256 + c0));
    }
    {   // hp ratio scalar * last row
        float s = (float)f[6] * (1.0f / 31.0f);
        float4 w = ld4(agg_w + (size_t)1347 * 256 + c0);
        acc.x += s * w.x; acc.y += s * w.y; acc.z += s * w.z; acc.w += s * w.w;
    }
    #pragma unroll
    for (int i = 0; i < 4; ++i)
        add4(acc, ld4(actions_emb + (size_t)f[34 + i] * 256 + c0));

    ushort4 o;
    o.x = f2bf(fmaxf(acc.x, 0.f));
    o.y = f2bf(fmaxf(acc.y, 0.f));
    o.z = f2bf(fmaxf(acc.z, 0.f));
    o.w = f2bf(fmaxf(acc.w, 0.f));
    *reinterpret_cast<ushort4*>(xr + (size_t)e * 256 + c0) = o;
}

// ---------------------------------------------------------------------------
// K2: out = relu_x(bf16) @ mlp_w + mlp_b, masked by species in {0,1}.
// MFMA 16x16x32 bf16: wave computes 16 rows x 256 cols (16 n-tiles).
// A lane l: A[l&15][k0 + 8*(l>>4) + j]; B lane l: B[k0+8*(l>>4)+j][l&15]
// (B read from wbt[c][k] transposed layout); D: col=l&15, row=4*(l>>4)+r.
// ---------------------------------------------------------------------------
__global__ __launch_bounds__(256) void k_mlp(
    const unsigned short* __restrict__ xr, const unsigned short* __restrict__ wbt,
    const float* __restrict__ mlp_b, const int* __restrict__ ent,
    float* __restrict__ out)
{
    int wave = (blockIdx.x << 2) + (threadIdx.x >> 6);
    int m0   = wave << 4;
    int lane = threadIdx.x & 63;
    int rc   = lane & 15;
    int kg   = lane >> 4;

    f32x4 acc[16];
    #pragma unroll
    for (int nt = 0; nt < 16; ++nt) acc[nt] = (f32x4){0.f, 0.f, 0.f, 0.f};

    #pragma unroll
    for (int k0 = 0; k0 < 256; k0 += 32) {
        bf16x8 a = *reinterpret_cast<const bf16x8*>(
            xr + (size_t)(m0 + rc) * 256 + k0 + kg * 8);
        #pragma unroll
        for (int nt = 0; nt < 16; ++nt) {
            bf16x8 b = *reinterpret_cast<const bf16x8*>(
                wbt + (size_t)(nt * 16 + rc) * 256 + k0 + kg * 8);
            acc[nt] = __builtin_amdgcn_mfma_f32_16x16x32_bf16(a, b, acc[nt], 0, 0, 0);
        }
    }

    int r0 = kg << 2;
    int spv[4];
    #pragma unroll
    for (int r = 0; r < 4; ++r) spv[r] = ent[(size_t)(m0 + r0 + r) * NFEAT];

    #pragma unroll
    for (int nt = 0; nt < 16; ++nt) {
        int col = (nt << 4) + rc;
        float bias = mlp_b[col];
        #pragma unroll
        for (int r = 0; r < 4; ++r) {
            int row = m0 + r0 + r;
            float v = acc[nt][r] + bias;
            out[(size_t)row * 256 + col] = (spv[r] == 0 || spv[r] == 1) ? 0.f : v;
        }
    }
}

// ---------------------------------------------------------------------------
extern "C" void kernel_launch(void* const* d_in, const int* in_sizes, int n_in,
                              void* d_out, int out_size, void* d_ws, size_t ws_size,
                              hipStream_t stream)
{
    const int*   ent     = (const int*)d_in[0];
    const float* sp_tbl  = (const float*)d_in[1];
    const float* ab_tbl  = (const float*)d_in[2];
    const float* it_tbl  = (const float*)d_in[3];
    const float* sp_emb  = (const float*)d_in[4];
    const float* ab_emb  = (const float*)d_in[5];
    const float* it_emb  = (const float*)d_in[6];
    const float* act_emb = (const float*)d_in[7];
    const float* agg_w   = (const float*)d_in[8];
    const float* agg_b   = (const float*)d_in[9];
    const float* mlp_w   = (const float*)d_in[10];
    const float* mlp_b   = (const float*)d_in[11];
    float* out = (float*)d_out;

    char* ws = (char*)d_ws;
    float*          fused = (float*)(ws);                       //   917,504 B (896*256*4)
    float*          btbl  = (float*)(ws + 917504);              // 5,767,168 B (22*256*256*4)
    unsigned short* wbt   = (unsigned short*)(ws + 6684672);    //   131,072 B (256*256*2)
    unsigned short* xr    = (unsigned short*)(ws + 6815744);    // 33,554,432 B (65536*256*2)

    k_fused <<<dim3(896),   dim3(256), 0, stream>>>(sp_tbl, ab_tbl, it_tbl,
                                                    sp_emb, ab_emb, it_emb,
                                                    agg_w, agg_b, fused);
    k_wbt   <<<dim3(256),   dim3(256), 0, stream>>>(mlp_w, wbt);
    k_btbl  <<<dim3(5632),  dim3(256), 0, stream>>>(agg_w, btbl);
    k_encode<<<dim3(16384), dim3(256), 0, stream>>>(ent, fused, btbl, agg_w, act_emb, xr);
    k_mlp   <<<dim3(1024),  dim3(256), 0, stream>>>(xr, wbt, mlp_b, ent, out);
}

// Round 3
// 188.923 us; speedup vs baseline: 1.4741x; 1.4741x over previous
//
#include <hip/hip_runtime.h>

#define NFEAT 38

typedef __attribute__((ext_vector_type(8))) short bf16x8;
typedef __attribute__((ext_vector_type(4))) float f32x4;

__device__ __forceinline__ unsigned short f2bf(float f) {
    unsigned int u = __float_as_uint(f);
    u += 0x7fffu + ((u >> 16) & 1u);   // round-to-nearest-even
    return (unsigned short)(u >> 16);
}

// Unified bf16 table `tbl` (rows of 256 cols, 512 B each):
//   [0,896)      fused species/ability/item (tbl@agg_w + emb [+ agg_b])
//   896  +101    f3 one-hot rows
//   997  +4      (f4,f5)
//   1001 +32     f6 one-hot + (v/31)*agg_w[1347] (hp folded)
//   1033 +24     (f7,f8)
//   1057 +32     (f9,f10)
//   1089 +4      (f11,f12)
//   1093 +64     (f13,f14,f15)
//   1157 +169    (f16,f17) boosts   1326 +169 (f18,f19)   1495 +169 (f20,f21)
//   1664 +13     f22
//   1677 +512    actions_emb (bf16)
//   2189 +5632   bits16 byte tables: row 2189 + fi*512 + half*256 + byte
// total rows = 7821

// ---------------------------------------------------------------------------
// K0a: fused rows 0..895, 4 rows per block.
// ---------------------------------------------------------------------------
__global__ __launch_bounds__(256) void k_fused(
    const float* __restrict__ sp_tbl, const float* __restrict__ ab_tbl,
    const float* __restrict__ it_tbl, const float* __restrict__ sp_emb,
    const float* __restrict__ ab_emb, const float* __restrict__ it_emb,
    const float* __restrict__ agg_w,  const float* __restrict__ agg_b,
    unsigned short* __restrict__ tbl)
{
    __shared__ float rowbuf[4][512];
    int r0 = blockIdx.x << 2, c = threadIdx.x;
    const float* src; const float* emb; int len, wbase; bool add_b;
    if (r0 < 512)      { src = sp_tbl + (size_t)r0 * 512;        emb = sp_emb + (size_t)r0 * 256;        len = 512; wbase = 0;   add_b = true;  }
    else if (r0 < 640) { int q = r0 - 512; src = ab_tbl + (size_t)q * 128; emb = ab_emb + (size_t)q * 256; len = 128; wbase = 512; add_b = false; }
    else               { int q = r0 - 640; src = it_tbl + (size_t)q * 256; emb = it_emb + (size_t)q * 256; len = 256; wbase = 640; add_b = false; }
    #pragma unroll
    for (int rr = 0; rr < 4; ++rr)
        for (int i = c; i < len; i += 256) rowbuf[rr][i] = src[rr * len + i];
    __syncthreads();
    float acc[4];
    float b = add_b ? agg_b[c] : 0.f;
    #pragma unroll
    for (int rr = 0; rr < 4; ++rr) acc[rr] = emb[rr * 256 + c] + b;
    #pragma unroll 4
    for (int k = 0; k < len; ++k) {
        float w = agg_w[(size_t)(wbase + k) * 256 + c];
        #pragma unroll
        for (int rr = 0; rr < 4; ++rr) acc[rr] += rowbuf[rr][k] * w;
    }
    #pragma unroll
    for (int rr = 0; rr < 4; ++rr)
        tbl[(size_t)(r0 + rr) * 256 + c] = f2bf(acc[rr]);
}

// ---------------------------------------------------------------------------
// K0b: all other prep, segmented by blockIdx:
//   [0,256)        wbt[c][k] = bf16(mlp_w[k][c])
//   [256,5888)     bits byte tables -> tbl rows 2189+
//   [5888,7181)    combo/one-hot/action rows -> tbl rows 896+r
// ---------------------------------------------------------------------------
__global__ __launch_bounds__(256) void k_prep(
    const float* __restrict__ agg_w, const float* __restrict__ mlp_w,
    const float* __restrict__ actions_emb,
    unsigned short* __restrict__ tbl, unsigned short* __restrict__ wbt)
{
    int blk = blockIdx.x, c = threadIdx.x;
    if (blk < 256) {                       // wbt (transposed bf16 mlp_w)
        wbt[(size_t)blk * 256 + c] = f2bf(mlp_w[(size_t)c * 256 + blk]);
        return;
    }
    if (blk < 5888) {                      // bits byte tables
        int t = (blk - 256) >> 8;          // 0..21  (= fi*2 + half)
        int byte = (blk - 256) & 255;
        int base = 1171 + 16 * (t >> 1) + 8 * (t & 1);
        float acc = 0.f;
        #pragma unroll
        for (int j = 0; j < 8; ++j)
            if ((byte >> j) & 1) acc += agg_w[(size_t)(base + j) * 256 + c];
        tbl[(size_t)(2189 + t * 256 + byte) * 256 + c] = f2bf(acc);
        return;
    }
    int r = blk - 5888;                    // 0..1292
    float acc;
    if (r < 101)      acc = agg_w[(size_t)(896 + r) * 256 + c];
    else if (r < 105) { int i = r - 101; acc = agg_w[(size_t)(997 + (i >> 1)) * 256 + c] + agg_w[(size_t)(999 + (i & 1)) * 256 + c]; }
    else if (r < 137) { int v = r - 105; acc = agg_w[(size_t)(1001 + v) * 256 + c] + (float)v * (1.f / 31.f) * agg_w[(size_t)1347 * 256 + c]; }
    else if (r < 161) { int i = r - 137; acc = agg_w[(size_t)(1033 + i / 8) * 256 + c] + agg_w[(size_t)(1036 + i % 8) * 256 + c]; }
    else if (r < 193) { int i = r - 161; acc = agg_w[(size_t)(1044 + (i >> 1)) * 256 + c] + agg_w[(size_t)(1060 + (i & 1)) * 256 + c]; }
    else if (r < 197) { int i = r - 193; acc = agg_w[(size_t)(1062 + (i >> 1)) * 256 + c] + agg_w[(size_t)(1064 + (i & 1)) * 256 + c]; }
    else if (r < 261) { int i = r - 197; acc = agg_w[(size_t)(1066 + (i >> 3)) * 256 + c] + agg_w[(size_t)(1074 + ((i >> 1) & 3)) * 256 + c] + agg_w[(size_t)(1078 + (i & 1)) * 256 + c]; }
    else if (r < 781) {
        int i = r - 261;
        if (i < 169)      acc = agg_w[(size_t)(1080 + i / 13) * 256 + c] + agg_w[(size_t)(1093 + i % 13) * 256 + c];
        else if (i < 338) { int j = i - 169; acc = agg_w[(size_t)(1106 + j / 13) * 256 + c] + agg_w[(size_t)(1119 + j % 13) * 256 + c]; }
        else if (i < 507) { int j = i - 338; acc = agg_w[(size_t)(1132 + j / 13) * 256 + c] + agg_w[(size_t)(1145 + j % 13) * 256 + c]; }
        else              { int j = i - 507; acc = agg_w[(size_t)(1158 + j) * 256 + c]; }
    }
    else { int i = r - 781; acc = actions_emb[(size_t)i * 256 + c]; }
    tbl[(size_t)(896 + r) * 256 + c] = f2bf(acc);
}

// ---------------------------------------------------------------------------
// K1: per-entity gather-sum over 40 bf16 rows -> relu -> bf16 xr.
// One wave per entity; lane covers cols [lane*4, lane*4+4).
// ---------------------------------------------------------------------------
__global__ __launch_bounds__(256) void k_encode(
    const int* __restrict__ ent, const unsigned short* __restrict__ tbl,
    unsigned short* __restrict__ xr)
{
    int e    = (blockIdx.x << 2) + (threadIdx.x >> 6);
    int lane = threadIdx.x & 63;
    int c4   = lane << 2;
    const int* f = ent + (size_t)e * NFEAT;

    int rows[40];
    rows[0] = f[0];
    rows[1] = 512 + f[1];
    rows[2] = 640 + f[2];
    rows[3] = 896 + f[3];
    rows[4] = 997 + f[4] * 2 + f[5];
    rows[5] = 1001 + f[6];
    rows[6] = 1033 + f[7] * 8 + f[8];
    rows[7] = 1057 + f[9] * 2 + f[10];
    rows[8] = 1089 + f[11] * 2 + f[12];
    rows[9] = 1093 + (f[13] * 4 + f[14]) * 2 + f[15];
    rows[10] = 1157 + f[16] * 13 + f[17];
    rows[11] = 1326 + f[18] * 13 + f[19];
    rows[12] = 1495 + f[20] * 13 + f[21];
    rows[13] = 1664 + f[22];
    #pragma unroll
    for (int i = 0; i < 11; ++i) {
        int v = f[23 + i];
        rows[14 + 2 * i] = 2189 + i * 512 + (v & 255);
        rows[15 + 2 * i] = 2189 + i * 512 + 256 + ((v >> 8) & 255);
    }
    #pragma unroll
    for (int i = 0; i < 4; ++i) rows[36 + i] = 1677 + f[34 + i];

    float4 acc = {0.f, 0.f, 0.f, 0.f};
    #pragma unroll
    for (int i = 0; i < 40; ++i) {
        uint2 u = *reinterpret_cast<const uint2*>(tbl + (size_t)rows[i] * 256 + c4);
        acc.x += __uint_as_float(u.x << 16);
        acc.y += __uint_as_float(u.x & 0xffff0000u);
        acc.z += __uint_as_float(u.y << 16);
        acc.w += __uint_as_float(u.y & 0xffff0000u);
    }

    unsigned int lo = (unsigned)f2bf(fmaxf(acc.x, 0.f)) | ((unsigned)f2bf(fmaxf(acc.y, 0.f)) << 16);
    unsigned int hi = (unsigned)f2bf(fmaxf(acc.z, 0.f)) | ((unsigned)f2bf(fmaxf(acc.w, 0.f)) << 16);
    *reinterpret_cast<uint2*>(xr + (size_t)e * 256 + c4) = make_uint2(lo, hi);
}

// ---------------------------------------------------------------------------
// K2: out = relu_x(bf16) @ mlp_w + mlp_b, masked by species in {0,1}.
// 32 rows per wave (two 16-row A tiles share each B fragment).
// ---------------------------------------------------------------------------
__global__ __launch_bounds__(256) void k_mlp(
    const unsigned short* __restrict__ xr, const unsigned short* __restrict__ wbt,
    const float* __restrict__ mlp_b, const int* __restrict__ ent,
    float* __restrict__ out)
{
    int wave = (blockIdx.x << 2) + (threadIdx.x >> 6);
    int m0   = wave << 5;
    int lane = threadIdx.x & 63;
    int rc   = lane & 15;
    int kg   = lane >> 4;

    f32x4 acc0[16], acc1[16];
    #pragma unroll
    for (int nt = 0; nt < 16; ++nt) {
        acc0[nt] = (f32x4){0.f, 0.f, 0.f, 0.f};
        acc1[nt] = (f32x4){0.f, 0.f, 0.f, 0.f};
    }

    #pragma unroll
    for (int k0 = 0; k0 < 256; k0 += 32) {
        bf16x8 a0 = *reinterpret_cast<const bf16x8*>(xr + (size_t)(m0 + rc) * 256 + k0 + kg * 8);
        bf16x8 a1 = *reinterpret_cast<const bf16x8*>(xr + (size_t)(m0 + 16 + rc) * 256 + k0 + kg * 8);
        #pragma unroll
        for (int nt = 0; nt < 16; ++nt) {
            bf16x8 b = *reinterpret_cast<const bf16x8*>(wbt + (size_t)(nt * 16 + rc) * 256 + k0 + kg * 8);
            acc0[nt] = __builtin_amdgcn_mfma_f32_16x16x32_bf16(a0, b, acc0[nt], 0, 0, 0);
            acc1[nt] = __builtin_amdgcn_mfma_f32_16x16x32_bf16(a1, b, acc1[nt], 0, 0, 0);
        }
    }

    int r0 = kg << 2;
    int spv0[4], spv1[4];
    #pragma unroll
    for (int r = 0; r < 4; ++r) {
        spv0[r] = ent[(size_t)(m0 + r0 + r) * NFEAT];
        spv1[r] = ent[(size_t)(m0 + 16 + r0 + r) * NFEAT];
    }

    #pragma unroll
    for (int nt = 0; nt < 16; ++nt) {
        int col = (nt << 4) + rc;
        float bias = mlp_b[col];
        #pragma unroll
        for (int r = 0; r < 4; ++r) {
            int row0 = m0 + r0 + r;
            int row1 = m0 + 16 + r0 + r;
            float v0 = acc0[nt][r] + bias;
            float v1 = acc1[nt][r] + bias;
            out[(size_t)row0 * 256 + col] = (spv0[r] == 0 || spv0[r] == 1) ? 0.f : v0;
            out[(size_t)row1 * 256 + col] = (spv1[r] == 0 || spv1[r] == 1) ? 0.f : v1;
        }
    }
}

// ---------------------------------------------------------------------------
extern "C" void kernel_launch(void* const* d_in, const int* in_sizes, int n_in,
                              void* d_out, int out_size, void* d_ws, size_t ws_size,
                              hipStream_t stream)
{
    const int*   ent     = (const int*)d_in[0];
    const float* sp_tbl  = (const float*)d_in[1];
    const float* ab_tbl  = (const float*)d_in[2];
    const float* it_tbl  = (const float*)d_in[3];
    const float* sp_emb  = (const float*)d_in[4];
    const float* ab_emb  = (const float*)d_in[5];
    const float* it_emb  = (const float*)d_in[6];
    const float* act_emb = (const float*)d_in[7];
    const float* agg_w   = (const float*)d_in[8];
    const float* agg_b   = (const float*)d_in[9];
    const float* mlp_w   = (const float*)d_in[10];
    const float* mlp_b   = (const float*)d_in[11];
    float* out = (float*)d_out;

    char* ws = (char*)d_ws;
    unsigned short* tbl = (unsigned short*)(ws);                 // 7821*512 = 4,004,352 B
    unsigned short* wbt = (unsigned short*)(ws + 4004352);       //   131,072 B
    unsigned short* xr  = (unsigned short*)(ws + 4135424);       // 33,554,432 B

    k_fused <<<dim3(224),   dim3(256), 0, stream>>>(sp_tbl, ab_tbl, it_tbl,
                                                    sp_emb, ab_emb, it_emb,
                                                    agg_w, agg_b, tbl);
    k_prep  <<<dim3(7181),  dim3(256), 0, stream>>>(agg_w, mlp_w, act_emb, tbl, wbt);
    k_encode<<<dim3(16384), dim3(256), 0, stream>>>(ent, tbl, xr);
    k_mlp   <<<dim3(512),   dim3(256), 0, stream>>>(xr, wbt, mlp_b, ent, out);
}

// Round 5
// 151.133 us; speedup vs baseline: 1.8427x; 1.2500x over previous
//
#include <hip/hip_runtime.h>

#define NFEAT 38

typedef __attribute__((ext_vector_type(8))) short bf16x8;
typedef __attribute__((ext_vector_type(4))) float f32x4;

// bf16 table row bases
#define R_SP   0      // 512 fused species rows
#define R_AB   512    // 128 fused ability rows
#define R_IT   640    // 256 fused item rows
#define R_T1   896    // 404: (f3,f4,f5)   = f3*4+f4*2+f5
#define R_T2   1300   // 128: (f6,f11,f12) = f6*4+f11*2+f12  (hp=f6/31 folded in)
#define R_T3   1428   // 24 : (f7,f8)      = f7*8+f8
#define R_T4   1452   // 32 : (f9,f10)     = f9*2+f10
#define R_T5   1484   // 64 : (f13,f14,f15)= f13*8+f14*2+f15
#define R_T6   1548   // 169: (f16,f17)    = f16*13+f17
#define R_T7   1717   // 169: (f18,f19)
#define R_T8   1886   // 169: (f20,f21)
#define R_T9   2055   // 13 : f22
#define R_ACT  2068   // 512: actions_emb (bf16)
#define R_BITS 2580   // 5632: 2580 + fi*512 + half*256 + byte
#define NROWS  8212   // total rows (x 512 B = 4,204,544 B)

__device__ __forceinline__ unsigned short f2bf(float f) {
    unsigned int u = __float_as_uint(f);
    u += 0x7fffu + ((u >> 16) & 1u);   // round-to-nearest-even
    return (unsigned short)(u >> 16);
}

// ---------------------------------------------------------------------------
// K0: ALL table prep in one kernel, segmented by blockIdx.x:
//   [0,256)        wbt[c][k] = bf16(mlp_w[k][c])
//   [256,5888)     bits byte tables
//   [5888,7572)    merged one-hot / boost / action rows
//   [7572,7796)    fused species/ability/item rows (4 rows per block)
// ---------------------------------------------------------------------------
__global__ __launch_bounds__(256) void k_prep(
    const float* __restrict__ sp_tbl, const float* __restrict__ ab_tbl,
    const float* __restrict__ it_tbl, const float* __restrict__ sp_emb,
    const float* __restrict__ ab_emb, const float* __restrict__ it_emb,
    const float* __restrict__ act_emb, const float* __restrict__ agg_w,
    const float* __restrict__ agg_b,  const float* __restrict__ mlp_w,
    unsigned short* __restrict__ tbl, unsigned short* __restrict__ wbt)
{
    __shared__ float rowbuf[4][512];
    int blk = blockIdx.x, c = threadIdx.x;
#define W(x) agg_w[(size_t)(x) * 256 + c]
    if (blk < 256) {                       // transposed bf16 mlp_w
        wbt[(size_t)blk * 256 + c] = f2bf(mlp_w[(size_t)c * 256 + blk]);
        return;
    }
    if (blk < 5888) {                      // bits byte tables
        int t = (blk - 256) >> 8;          // fi*2 + half
        int byte = (blk - 256) & 255;
        int base = 1171 + 16 * (t >> 1) + 8 * (t & 1);
        float acc = 0.f;
        #pragma unroll
        for (int j = 0; j < 8; ++j)
            if ((byte >> j) & 1) acc += W(base + j);
        tbl[(size_t)(R_BITS + t * 256 + byte) * 256 + c] = f2bf(acc);
        return;
    }
    if (blk < 7572) {                      // merged category rows
        int r = blk - 5888; int row; float acc;
        if (r < 404)       { int f3 = r >> 2, f4 = (r >> 1) & 1, f5 = r & 1;
                             acc = W(896 + f3) + W(997 + f4) + W(999 + f5); row = R_T1 + r; }
        else if (r < 532)  { int i = r - 404; int f6 = i >> 2, f11 = (i >> 1) & 1, f12 = i & 1;
                             acc = W(1001 + f6) + (float)f6 * (1.f / 31.f) * W(1347)
                                 + W(1062 + f11) + W(1064 + f12); row = R_T2 + i; }
        else if (r < 556)  { int i = r - 532; acc = W(1033 + (i >> 3)) + W(1036 + (i & 7)); row = R_T3 + i; }
        else if (r < 588)  { int i = r - 556; acc = W(1044 + (i >> 1)) + W(1060 + (i & 1)); row = R_T4 + i; }
        else if (r < 652)  { int i = r - 588; acc = W(1066 + (i >> 3)) + W(1074 + ((i >> 1) & 3)) + W(1078 + (i & 1)); row = R_T5 + i; }
        else if (r < 821)  { int i = r - 652; acc = W(1080 + i / 13) + W(1093 + i % 13); row = R_T6 + i; }
        else if (r < 990)  { int i = r - 821; acc = W(1106 + i / 13) + W(1119 + i % 13); row = R_T7 + i; }
        else if (r < 1159) { int i = r - 990; acc = W(1132 + i / 13) + W(1145 + i % 13); row = R_T8 + i; }
        else if (r < 1172) { int i = r - 1159; acc = W(1158 + i); row = R_T9 + i; }
        else               { int i = r - 1172; acc = act_emb[(size_t)i * 256 + c]; row = R_ACT + i; }
        tbl[(size_t)row * 256 + c] = f2bf(acc);
        return;
    }
    // fused species/ability/item: tbl-row @ agg_w + emb (+ agg_b for species)
    int r0 = (blk - 7572) << 2;
    const float* src; const float* emb; int len, wbase; bool add_b;
    if (r0 < 512)      { src = sp_tbl + (size_t)r0 * 512;           emb = sp_emb + (size_t)r0 * 256;           len = 512; wbase = 0;   add_b = true;  }
    else if (r0 < 640) { int q = r0 - 512; src = ab_tbl + (size_t)q * 128; emb = ab_emb + (size_t)q * 256; len = 128; wbase = 512; add_b = false; }
    else               { int q = r0 - 640; src = it_tbl + (size_t)q * 256; emb = it_emb + (size_t)q * 256; len = 256; wbase = 640; add_b = false; }
    #pragma unroll
    for (int rr = 0; rr < 4; ++rr)
        for (int i = c; i < len; i += 256) rowbuf[rr][i] = src[rr * len + i];
    __syncthreads();
    float acc[4];
    float b = add_b ? agg_b[c] : 0.f;
    #pragma unroll
    for (int rr = 0; rr < 4; ++rr) acc[rr] = emb[rr * 256 + c] + b;
    #pragma unroll 4
    for (int k = 0; k < len; ++k) {
        float w = W(wbase + k);
        #pragma unroll
        for (int rr = 0; rr < 4; ++rr) acc[rr] += rowbuf[rr][k] * w;
    }
    #pragma unroll
    for (int rr = 0; rr < 4; ++rr)
        tbl[(size_t)(r0 + rr) * 256 + c] = f2bf(acc[rr]);
#undef W
}

// ---------------------------------------------------------------------------
// K1: per-entity row-index precompute -> packed ushort[40] (80 B, 16B-aligned)
// ---------------------------------------------------------------------------
__global__ __launch_bounds__(256) void k_idx(
    const int* __restrict__ ent, unsigned short* __restrict__ ridx)
{
    int e = blockIdx.x * 256 + threadIdx.x;
    const int* f = ent + (size_t)e * NFEAT;
    unsigned short r[40];
    r[0] = (unsigned short)f[0];
    r[1] = (unsigned short)(R_AB + f[1]);
    r[2] = (unsigned short)(R_IT + f[2]);
    r[3] = (unsigned short)(R_T1 + f[3] * 4 + f[4] * 2 + f[5]);
    r[4] = (unsigned short)(R_T2 + f[6] * 4 + f[11] * 2 + f[12]);
    r[5] = (unsigned short)(R_T3 + f[7] * 8 + f[8]);
    r[6] = (unsigned short)(R_T4 + f[9] * 2 + f[10]);
    r[7] = (unsigned short)(R_T5 + f[13] * 8 + f[14] * 2 + f[15]);
    r[8] = (unsigned short)(R_T6 + f[16] * 13 + f[17]);
    r[9] = (unsigned short)(R_T7 + f[18] * 13 + f[19]);
    r[10] = (unsigned short)(R_T8 + f[20] * 13 + f[21]);
    r[11] = (unsigned short)(R_T9 + f[22]);
    #pragma unroll
    for (int i = 0; i < 11; ++i) {
        int v = f[23 + i];
        r[12 + 2 * i] = (unsigned short)(R_BITS + i * 512 + (v & 255));
        r[13 + 2 * i] = (unsigned short)(R_BITS + i * 512 + 256 + ((v >> 8) & 255));
    }
    #pragma unroll
    for (int i = 0; i < 4; ++i) r[34 + i] = (unsigned short)(R_ACT + f[34 + i]);
    r[38] = 0; r[39] = 0;
    unsigned int p[20];
    #pragma unroll
    for (int i = 0; i < 20; ++i)
        p[i] = (unsigned int)r[2 * i] | ((unsigned int)r[2 * i + 1] << 16);
    uint4* dst = reinterpret_cast<uint4*>(ridx + (size_t)e * 40);
    dst[0] = make_uint4(p[0], p[1], p[2], p[3]);
    dst[1] = make_uint4(p[4], p[5], p[6], p[7]);
    dst[2] = make_uint4(p[8], p[9], p[10], p[11]);
    dst[3] = make_uint4(p[12], p[13], p[14], p[15]);
    dst[4] = make_uint4(p[16], p[17], p[18], p[19]);
}

// ---------------------------------------------------------------------------
// K2: gather-sum of 38 bf16 rows, 2 rows per dwordx4 load inst.
// Wave = 1 entity. Lanes 0-31: even rows, lanes 32-63: odd rows;
// lane covers cols [ (lane&31)*8, +8 ).  Cross-half combine via shfl_xor(32).
// ---------------------------------------------------------------------------
__global__ __launch_bounds__(256) void k_encode(
    const unsigned short* __restrict__ ridx, const unsigned short* __restrict__ tbl,
    unsigned short* __restrict__ xr)
{
    int e    = (blockIdx.x << 2) + (threadIdx.x >> 6);
    int lane = threadIdx.x & 63;
    int half = lane >> 5;
    int cp   = lane & 31;
    int cb   = cp << 4;                       // byte offset of lane's 8 cols

    const uint4* rp = reinterpret_cast<const uint4*>(ridx + (size_t)e * 40);
    uint4 w0 = rp[0], w1 = rp[1], w2 = rp[2], w3 = rp[3], w4 = rp[4];
    unsigned int idx32[19] = {w0.x, w0.y, w0.z, w0.w, w1.x, w1.y, w1.z, w1.w,
                              w2.x, w2.y, w2.z, w2.w, w3.x, w3.y, w3.z, w3.w,
                              w4.x, w4.y, w4.z};
    const char* tb = reinterpret_cast<const char*>(tbl);
    int sh = half << 4;

    float acc[8] = {0.f, 0.f, 0.f, 0.f, 0.f, 0.f, 0.f, 0.f};
    #pragma unroll
    for (int i = 0; i < 19; ++i) {
        unsigned int row = (idx32[i] >> sh) & 0xffffu;
        uint4 v = *reinterpret_cast<const uint4*>(tb + ((size_t)row << 9) + cb);
        acc[0] += __uint_as_float(v.x << 16);
        acc[1] += __uint_as_float(v.x & 0xffff0000u);
        acc[2] += __uint_as_float(v.y << 16);
        acc[3] += __uint_as_float(v.y & 0xffff0000u);
        acc[4] += __uint_as_float(v.z << 16);
        acc[5] += __uint_as_float(v.z & 0xffff0000u);
        acc[6] += __uint_as_float(v.w << 16);
        acc[7] += __uint_as_float(v.w & 0xffff0000u);
    }
    #pragma unroll
    for (int i = 0; i < 8; ++i) acc[i] += __shfl_xor(acc[i], 32);

    if (half == 0) {
        unsigned int o0 = (unsigned)f2bf(fmaxf(acc[0], 0.f)) | ((unsigned)f2bf(fmaxf(acc[1], 0.f)) << 16);
        unsigned int o1 = (unsigned)f2bf(fmaxf(acc[2], 0.f)) | ((unsigned)f2bf(fmaxf(acc[3], 0.f)) << 16);
        unsigned int o2 = (unsigned)f2bf(fmaxf(acc[4], 0.f)) | ((unsigned)f2bf(fmaxf(acc[5], 0.f)) << 16);
        unsigned int o3 = (unsigned)f2bf(fmaxf(acc[6], 0.f)) | ((unsigned)f2bf(fmaxf(acc[7], 0.f)) << 16);
        *reinterpret_cast<uint4*>(xr + (size_t)e * 256 + (cp << 3)) = make_uint4(o0, o1, o2, o3);
    }
}

// ---------------------------------------------------------------------------
// K3: out = relu_x(bf16) @ mlp_w + mlp_b, masked by species in {0,1}.
// 32 rows per wave (two 16-row A tiles share each B fragment).
// ---------------------------------------------------------------------------
__global__ __launch_bounds__(256) void k_mlp(
    const unsigned short* __restrict__ xr, const unsigned short* __restrict__ wbt,
    const float* __restrict__ mlp_b, const int* __restrict__ ent,
    float* __restrict__ out)
{
    int wave = (blockIdx.x << 2) + (threadIdx.x >> 6);
    int m0   = wave << 5;
    int lane = threadIdx.x & 63;
    int rc   = lane & 15;
    int kg   = lane >> 4;

    f32x4 acc0[16], acc1[16];
    #pragma unroll
    for (int nt = 0; nt < 16; ++nt) {
        acc0[nt] = (f32x4){0.f, 0.f, 0.f, 0.f};
        acc1[nt] = (f32x4){0.f, 0.f, 0.f, 0.f};
    }

    #pragma unroll
    for (int k0 = 0; k0 < 256; k0 += 32) {
        bf16x8 a0 = *reinterpret_cast<const bf16x8*>(xr + (size_t)(m0 + rc) * 256 + k0 + kg * 8);
        bf16x8 a1 = *reinterpret_cast<const bf16x8*>(xr + (size_t)(m0 + 16 + rc) * 256 + k0 + kg * 8);
        #pragma unroll
        for (int nt = 0; nt < 16; ++nt) {
            bf16x8 b = *reinterpret_cast<const bf16x8*>(wbt + (size_t)(nt * 16 + rc) * 256 + k0 + kg * 8);
            acc0[nt] = __builtin_amdgcn_mfma_f32_16x16x32_bf16(a0, b, acc0[nt], 0, 0, 0);
            acc1[nt] = __builtin_amdgcn_mfma_f32_16x16x32_bf16(a1, b, acc1[nt], 0, 0, 0);
        }
    }

    int r0 = kg << 2;
    int spv0[4], spv1[4];
    #pragma unroll
    for (int r = 0; r < 4; ++r) {
        spv0[r] = ent[(size_t)(m0 + r0 + r) * NFEAT];
        spv1[r] = ent[(size_t)(m0 + 16 + r0 + r) * NFEAT];
    }

    #pragma unroll
    for (int nt = 0; nt < 16; ++nt) {
        int col = (nt << 4) + rc;
        float bias = mlp_b[col];
        #pragma unroll
        for (int r = 0; r < 4; ++r) {
            int row0 = m0 + r0 + r;
            int row1 = m0 + 16 + r0 + r;
            float v0 = acc0[nt][r] + bias;
            float v1 = acc1[nt][r] + bias;
            out[(size_t)row0 * 256 + col] = (spv0[r] == 0 || spv0[r] == 1) ? 0.f : v0;
            out[(size_t)row1 * 256 + col] = (spv1[r] == 0 || spv1[r] == 1) ? 0.f : v1;
        }
    }
}

// ---------------------------------------------------------------------------
extern "C" void kernel_launch(void* const* d_in, const int* in_sizes, int n_in,
                              void* d_out, int out_size, void* d_ws, size_t ws_size,
                              hipStream_t stream)
{
    const int*   ent     = (const int*)d_in[0];
    const float* sp_tbl  = (const float*)d_in[1];
    const float* ab_tbl  = (const float*)d_in[2];
    const float* it_tbl  = (const float*)d_in[3];
    const float* sp_emb  = (const float*)d_in[4];
    const float* ab_emb  = (const float*)d_in[5];
    const float* it_emb  = (const float*)d_in[6];
    const float* act_emb = (const float*)d_in[7];
    const float* agg_w   = (const float*)d_in[8];
    const float* agg_b   = (const float*)d_in[9];
    const float* mlp_w   = (const float*)d_in[10];
    const float* mlp_b   = (const float*)d_in[11];
    float* out = (float*)d_out;

    char* ws = (char*)d_ws;
    unsigned short* tbl  = (unsigned short*)(ws);                // 8212*512 = 4,204,544 B
    unsigned short* wbt  = (unsigned short*)(ws + 4204544);      //   131,072 B
    unsigned short* ridx = (unsigned short*)(ws + 4335616);      // 65536*80 = 5,242,880 B
    unsigned short* xr   = (unsigned short*)(ws + 9578496);      // 33,554,432 B

    k_prep  <<<dim3(7796),  dim3(256), 0, stream>>>(sp_tbl, ab_tbl, it_tbl,
                                                    sp_emb, ab_emb, it_emb,
                                                    act_emb, agg_w, agg_b, mlp_w,
                                                    tbl, wbt);
    k_idx   <<<dim3(256),   dim3(256), 0, stream>>>(ent, ridx);
    k_encode<<<dim3(16384), dim3(256), 0, stream>>>(ridx, tbl, xr);
    k_mlp   <<<dim3(512),   dim3(256), 0, stream>>>(xr, wbt, mlp_b, ent, out);
}

// Round 6
// 123.939 us; speedup vs baseline: 2.2470x; 1.2194x over previous
//
#include <hip/hip_runtime.h>

#define NFEAT 38

typedef __attribute__((ext_vector_type(8))) short bf16x8;
typedef __attribute__((ext_vector_type(4))) float f32x4;

// bf16 table row bases
#define R_SP   0      // 512 fused species rows
#define R_AB   512    // 128 fused ability rows
#define R_IT   640    // 256 fused item rows
#define R_T1   896    // 404: (f3,f4,f5)   = f3*4+f4*2+f5
#define R_T2   1300   // 128: (f6,f11,f12) = f6*4+f11*2+f12  (hp=f6/31 folded in)
#define R_T3   1428   // 24 : (f7,f8)      = f7*8+f8
#define R_T4   1452   // 32 : (f9,f10)     = f9*2+f10
#define R_T5   1484   // 64 : (f13,f14,f15)= f13*8+f14*2+f15
#define R_T6   1548   // 169: (f16,f17)    = f16*13+f17
#define R_T7   1717   // 169: (f18,f19)
#define R_T8   1886   // 169: (f20,f21)
#define R_T9   2055   // 13 : f22
#define R_ACT  2068   // 512: actions_emb (bf16)
#define R_BITS 2580   // 5632: 2580 + fi*512 + half*256 + byte
#define NROWS  8212   // total rows (x 512 B = 4,204,544 B)

// k_prep block layout (1024 threads each)
#define B_FUSED  0     // 224 blocks: fused sp/ab/it rows (4 rows, 4-way K-split)
#define B_IDX    224   // 64 blocks : per-entity row-index precompute
#define B_WBT    288   // 64 blocks : transposed bf16 mlp_w
#define B_BITS   352   // 1408 blocks: bits byte tables (4 rows/block)
#define B_MERGED 1760  // 421 blocks: merged one-hot/boost/action rows (4 rows/block)
#define NB_PREP  2181

__device__ __forceinline__ unsigned short f2bf(float f) {
    unsigned int u = __float_as_uint(f);
    u += 0x7fffu + ((u >> 16) & 1u);   // round-to-nearest-even
    return (unsigned short)(u >> 16);
}

// ---------------------------------------------------------------------------
// K0: ALL prep in one kernel, 1024-thread blocks, fused blocks first.
// ---------------------------------------------------------------------------
__global__ __launch_bounds__(1024) void k_prep(
    const float* __restrict__ sp_tbl, const float* __restrict__ ab_tbl,
    const float* __restrict__ it_tbl, const float* __restrict__ sp_emb,
    const float* __restrict__ ab_emb, const float* __restrict__ it_emb,
    const float* __restrict__ act_emb, const float* __restrict__ agg_w,
    const float* __restrict__ agg_b,  const float* __restrict__ mlp_w,
    const int* __restrict__ ent,
    unsigned short* __restrict__ tbl, unsigned short* __restrict__ wbt,
    unsigned short* __restrict__ ridx)
{
    __shared__ float rowbuf[4 * 512];
    __shared__ float part[4][4][256];
    int blk = blockIdx.x, t = threadIdx.x, c = t & 255;
#define W(x) agg_w[(size_t)(x) * 256 + c]

    if (blk < B_IDX) {
        // ---- fused species/ability/item rows: 4 rows/block, K split 4 ways ----
        int r0 = blk << 2;
        const float* src; const float* emb; int len, wbase; bool add_b;
        if (r0 < 512)      { src = sp_tbl + (size_t)r0 * 512;           emb = sp_emb + (size_t)r0 * 256;           len = 512; wbase = 0;   add_b = true;  }
        else if (r0 < 640) { int q = r0 - 512; src = ab_tbl + (size_t)q * 128; emb = ab_emb + (size_t)q * 256; len = 128; wbase = 512; add_b = false; }
        else               { int q = r0 - 640; src = it_tbl + (size_t)q * 256; emb = it_emb + (size_t)q * 256; len = 256; wbase = 640; add_b = false; }
        int tot = len << 2;
        for (int i = t; i < tot; i += 1024) rowbuf[i] = src[i];
        __syncthreads();
        int kq   = t >> 8;
        int len4 = len >> 2;
        int kbeg = kq * len4, kend = kbeg + len4;
        float a0 = 0.f, a1 = 0.f, a2 = 0.f, a3 = 0.f;
        #pragma unroll 4
        for (int k = kbeg; k < kend; ++k) {
            float w = W(wbase + k);
            a0 += rowbuf[k] * w;
            a1 += rowbuf[len + k] * w;
            a2 += rowbuf[2 * len + k] * w;
            a3 += rowbuf[3 * len + k] * w;
        }
        part[0][kq][c] = a0; part[1][kq][c] = a1;
        part[2][kq][c] = a2; part[3][kq][c] = a3;
        __syncthreads();
        int row = t >> 8;
        float s = part[row][0][c] + part[row][1][c] + part[row][2][c] + part[row][3][c]
                + emb[row * 256 + c] + (add_b ? agg_b[c] : 0.f);
        tbl[(size_t)(r0 + row) * 256 + c] = f2bf(s);
        return;
    }
    if (blk < B_WBT) {
        // ---- per-entity packed row indices (was k_idx) ----
        int e = ((blk - B_IDX) << 10) + t;
        const int* f = ent + (size_t)e * NFEAT;
        unsigned short r[40];
        r[0] = (unsigned short)f[0];
        r[1] = (unsigned short)(R_AB + f[1]);
        r[2] = (unsigned short)(R_IT + f[2]);
        r[3] = (unsigned short)(R_T1 + f[3] * 4 + f[4] * 2 + f[5]);
        r[4] = (unsigned short)(R_T2 + f[6] * 4 + f[11] * 2 + f[12]);
        r[5] = (unsigned short)(R_T3 + f[7] * 8 + f[8]);
        r[6] = (unsigned short)(R_T4 + f[9] * 2 + f[10]);
        r[7] = (unsigned short)(R_T5 + f[13] * 8 + f[14] * 2 + f[15]);
        r[8] = (unsigned short)(R_T6 + f[16] * 13 + f[17]);
        r[9] = (unsigned short)(R_T7 + f[18] * 13 + f[19]);
        r[10] = (unsigned short)(R_T8 + f[20] * 13 + f[21]);
        r[11] = (unsigned short)(R_T9 + f[22]);
        #pragma unroll
        for (int i = 0; i < 11; ++i) {
            int v = f[23 + i];
            r[12 + 2 * i] = (unsigned short)(R_BITS + i * 512 + (v & 255));
            r[13 + 2 * i] = (unsigned short)(R_BITS + i * 512 + 256 + ((v >> 8) & 255));
        }
        #pragma unroll
        for (int i = 0; i < 4; ++i) r[34 + i] = (unsigned short)(R_ACT + f[34 + i]);
        r[38] = 0; r[39] = 0;
        unsigned int p[20];
        #pragma unroll
        for (int i = 0; i < 20; ++i)
            p[i] = (unsigned int)r[2 * i] | ((unsigned int)r[2 * i + 1] << 16);
        uint4* dst = reinterpret_cast<uint4*>(ridx + (size_t)e * 40);
        dst[0] = make_uint4(p[0], p[1], p[2], p[3]);
        dst[1] = make_uint4(p[4], p[5], p[6], p[7]);
        dst[2] = make_uint4(p[8], p[9], p[10], p[11]);
        dst[3] = make_uint4(p[12], p[13], p[14], p[15]);
        dst[4] = make_uint4(p[16], p[17], p[18], p[19]);
        return;
    }
    if (blk < B_BITS) {
        // ---- transposed bf16 mlp_w ----
        int idx = ((blk - B_WBT) << 10) + t;
        int col = idx >> 8, k = idx & 255;
        wbt[(size_t)col * 256 + k] = f2bf(mlp_w[(size_t)k * 256 + col]);
        return;
    }
    if (blk < B_MERGED) {
        // ---- bits byte tables: 4 rows per block ----
        int idx = ((blk - B_BITS) << 10) + t;
        int row = idx >> 8;                 // 0..5631 = tseg*256 + byte
        int tseg = row >> 8, byte = row & 255;
        int base = 1171 + 16 * (tseg >> 1) + 8 * (tseg & 1);
        float acc = 0.f;
        #pragma unroll
        for (int j = 0; j < 8; ++j)
            if ((byte >> j) & 1) acc += W(base + j);
        tbl[(size_t)(R_BITS + row) * 256 + c] = f2bf(acc);
        return;
    }
    {
        // ---- merged category rows: 4 rows per block ----
        int r = ((blk - B_MERGED) << 2) + (t >> 8);   // 0..1683
        int row; float acc;
        if (r < 404)       { int f3 = r >> 2, f4 = (r >> 1) & 1, f5 = r & 1;
                             acc = W(896 + f3) + W(997 + f4) + W(999 + f5); row = R_T1 + r; }
        else if (r < 532)  { int i = r - 404; int f6 = i >> 2, f11 = (i >> 1) & 1, f12 = i & 1;
                             acc = W(1001 + f6) + (float)f6 * (1.f / 31.f) * W(1347)
                                 + W(1062 + f11) + W(1064 + f12); row = R_T2 + i; }
        else if (r < 556)  { int i = r - 532; acc = W(1033 + (i >> 3)) + W(1036 + (i & 7)); row = R_T3 + i; }
        else if (r < 588)  { int i = r - 556; acc = W(1044 + (i >> 1)) + W(1060 + (i & 1)); row = R_T4 + i; }
        else if (r < 652)  { int i = r - 588; acc = W(1066 + (i >> 3)) + W(1074 + ((i >> 1) & 3)) + W(1078 + (i & 1)); row = R_T5 + i; }
        else if (r < 821)  { int i = r - 652; acc = W(1080 + i / 13) + W(1093 + i % 13); row = R_T6 + i; }
        else if (r < 990)  { int i = r - 821; acc = W(1106 + i / 13) + W(1119 + i % 13); row = R_T7 + i; }
        else if (r < 1159) { int i = r - 990; acc = W(1132 + i / 13) + W(1145 + i % 13); row = R_T8 + i; }
        else if (r < 1172) { int i = r - 1159; acc = W(1158 + i); row = R_T9 + i; }
        else               { int i = r - 1172; acc = act_emb[(size_t)i * 256 + c]; row = R_ACT + i; }
        tbl[(size_t)row * 256 + c] = f2bf(acc);
    }
#undef W
}

// ---------------------------------------------------------------------------
// K1: gather-sum of 38 bf16 rows, 2 rows per dwordx4 load inst.
// Wave = 1 entity. Lanes 0-31: even rows, lanes 32-63: odd rows;
// lane covers cols [ (lane&31)*8, +8 ).  Cross-half combine via shfl_xor(32).
// ---------------------------------------------------------------------------
__global__ __launch_bounds__(256) void k_encode(
    const unsigned short* __restrict__ ridx, const unsigned short* __restrict__ tbl,
    unsigned short* __restrict__ xr)
{
    int e    = (blockIdx.x << 2) + (threadIdx.x >> 6);
    int lane = threadIdx.x & 63;
    int half = lane >> 5;
    int cp   = lane & 31;
    int cb   = cp << 4;                       // byte offset of lane's 8 cols

    const uint4* rp = reinterpret_cast<const uint4*>(ridx + (size_t)e * 40);
    uint4 w0 = rp[0], w1 = rp[1], w2 = rp[2], w3 = rp[3], w4 = rp[4];
    unsigned int idx32[19] = {w0.x, w0.y, w0.z, w0.w, w1.x, w1.y, w1.z, w1.w,
                              w2.x, w2.y, w2.z, w2.w, w3.x, w3.y, w3.z, w3.w,
                              w4.x, w4.y, w4.z};
    const char* tb = reinterpret_cast<const char*>(tbl);
    int sh = half << 4;

    float acc[8] = {0.f, 0.f, 0.f, 0.f, 0.f, 0.f, 0.f, 0.f};
    #pragma unroll
    for (int i = 0; i < 19; ++i) {
        unsigned int row = (idx32[i] >> sh) & 0xffffu;
        uint4 v = *reinterpret_cast<const uint4*>(tb + ((size_t)row << 9) + cb);
        acc[0] += __uint_as_float(v.x << 16);
        acc[1] += __uint_as_float(v.x & 0xffff0000u);
        acc[2] += __uint_as_float(v.y << 16);
        acc[3] += __uint_as_float(v.y & 0xffff0000u);
        acc[4] += __uint_as_float(v.z << 16);
        acc[5] += __uint_as_float(v.z & 0xffff0000u);
        acc[6] += __uint_as_float(v.w << 16);
        acc[7] += __uint_as_float(v.w & 0xffff0000u);
    }
    #pragma unroll
    for (int i = 0; i < 8; ++i) acc[i] += __shfl_xor(acc[i], 32);

    if (half == 0) {
        unsigned int o0 = (unsigned)f2bf(fmaxf(acc[0], 0.f)) | ((unsigned)f2bf(fmaxf(acc[1], 0.f)) << 16);
        unsigned int o1 = (unsigned)f2bf(fmaxf(acc[2], 0.f)) | ((unsigned)f2bf(fmaxf(acc[3], 0.f)) << 16);
        unsigned int o2 = (unsigned)f2bf(fmaxf(acc[4], 0.f)) | ((unsigned)f2bf(fmaxf(acc[5], 0.f)) << 16);
        unsigned int o3 = (unsigned)f2bf(fmaxf(acc[6], 0.f)) | ((unsigned)f2bf(fmaxf(acc[7], 0.f)) << 16);
        *reinterpret_cast<uint4*>(xr + (size_t)e * 256 + (cp << 3)) = make_uint4(o0, o1, o2, o3);
    }
}

// ---------------------------------------------------------------------------
// K2: out = relu_x(bf16) @ mlp_w + mlp_b, masked by species in {0,1}.
// 32 rows per wave (two 16-row A tiles share each B fragment).
// ---------------------------------------------------------------------------
__global__ __launch_bounds__(256) void k_mlp(
    const unsigned short* __restrict__ xr, const unsigned short* __restrict__ wbt,
    const float* __restrict__ mlp_b, const int* __restrict__ ent,
    float* __restrict__ out)
{
    int wave = (blockIdx.x << 2) + (threadIdx.x >> 6);
    int m0   = wave << 5;
    int lane = threadIdx.x & 63;
    int rc   = lane & 15;
    int kg   = lane >> 4;

    f32x4 acc0[16], acc1[16];
    #pragma unroll
    for (int nt = 0; nt < 16; ++nt) {
        acc0[nt] = (f32x4){0.f, 0.f, 0.f, 0.f};
        acc1[nt] = (f32x4){0.f, 0.f, 0.f, 0.f};
    }

    #pragma unroll
    for (int k0 = 0; k0 < 256; k0 += 32) {
        bf16x8 a0 = *reinterpret_cast<const bf16x8*>(xr + (size_t)(m0 + rc) * 256 + k0 + kg * 8);
        bf16x8 a1 = *reinterpret_cast<const bf16x8*>(xr + (size_t)(m0 + 16 + rc) * 256 + k0 + kg * 8);
        #pragma unroll
        for (int nt = 0; nt < 16; ++nt) {
            bf16x8 b = *reinterpret_cast<const bf16x8*>(wbt + (size_t)(nt * 16 + rc) * 256 + k0 + kg * 8);
            acc0[nt] = __builtin_amdgcn_mfma_f32_16x16x32_bf16(a0, b, acc0[nt], 0, 0, 0);
            acc1[nt] = __builtin_amdgcn_mfma_f32_16x16x32_bf16(a1, b, acc1[nt], 0, 0, 0);
        }
    }

    int r0 = kg << 2;
    int spv0[4], spv1[4];
    #pragma unroll
    for (int r = 0; r < 4; ++r) {
        spv0[r] = ent[(size_t)(m0 + r0 + r) * NFEAT];
        spv1[r] = ent[(size_t)(m0 + 16 + r0 + r) * NFEAT];
    }

    #pragma unroll
    for (int nt = 0; nt < 16; ++nt) {
        int col = (nt << 4) + rc;
        float bias = mlp_b[col];
        #pragma unroll
        for (int r = 0; r < 4; ++r) {
            int row0 = m0 + r0 + r;
            int row1 = m0 + 16 + r0 + r;
            float v0 = acc0[nt][r] + bias;
            float v1 = acc1[nt][r] + bias;
            out[(size_t)row0 * 256 + col] = (spv0[r] == 0 || spv0[r] == 1) ? 0.f : v0;
            out[(size_t)row1 * 256 + col] = (spv1[r] == 0 || spv1[r] == 1) ? 0.f : v1;
        }
    }
}

// ---------------------------------------------------------------------------
extern "C" void kernel_launch(void* const* d_in, const int* in_sizes, int n_in,
                              void* d_out, int out_size, void* d_ws, size_t ws_size,
                              hipStream_t stream)
{
    const int*   ent     = (const int*)d_in[0];
    const float* sp_tbl  = (const float*)d_in[1];
    const float* ab_tbl  = (const float*)d_in[2];
    const float* it_tbl  = (const float*)d_in[3];
    const float* sp_emb  = (const float*)d_in[4];
    const float* ab_emb  = (const float*)d_in[5];
    const float* it_emb  = (const float*)d_in[6];
    const float* act_emb = (const float*)d_in[7];
    const float* agg_w   = (const float*)d_in[8];
    const float* agg_b   = (const float*)d_in[9];
    const float* mlp_w   = (const float*)d_in[10];
    const float* mlp_b   = (const float*)d_in[11];
    float* out = (float*)d_out;

    char* ws = (char*)d_ws;
    unsigned short* tbl  = (unsigned short*)(ws);                // 8212*512 = 4,204,544 B
    unsigned short* wbt  = (unsigned short*)(ws + 4204544);      //   131,072 B
    unsigned short* ridx = (unsigned short*)(ws + 4335616);      // 65536*80 = 5,242,880 B
    unsigned short* xr   = (unsigned short*)(ws + 9578496);      // 33,554,432 B

    k_prep  <<<dim3(NB_PREP), dim3(1024), 0, stream>>>(sp_tbl, ab_tbl, it_tbl,
                                                       sp_emb, ab_emb, it_emb,
                                                       act_emb, agg_w, agg_b, mlp_w,
                                                       ent, tbl, wbt, ridx);
    k_encode<<<dim3(16384),   dim3(256),  0, stream>>>(ridx, tbl, xr);
    k_mlp   <<<dim3(512),     dim3(256),  0, stream>>>(xr, wbt, mlp_b, ent, out);
}

// Round 7
// 103.989 us; speedup vs baseline: 2.6781x; 1.1918x over previous
//
#include <hip/hip_runtime.h>

#define NFEAT 38

typedef __attribute__((ext_vector_type(8))) short bf16x8;
typedef __attribute__((ext_vector_type(4))) float f32x4;

// bf16 table row bases
#define R_SP   0      // 512 fused species rows
#define R_AB   512    // 128 fused ability rows
#define R_IT   640    // 256 fused item rows
#define R_T1   896    // 404: (f3,f4,f5)   = f3*4+f4*2+f5
#define R_T2   1300   // 128: (f6,f11,f12) = f6*4+f11*2+f12  (hp=f6/31 folded in)
#define R_T3   1428   // 24 : (f7,f8)      = f7*8+f8
#define R_T4   1452   // 32 : (f9,f10)     = f9*2+f10
#define R_T5   1484   // 64 : (f13,f14,f15)= f13*8+f14*2+f15
#define R_T6   1548   // 169: (f16,f17)    = f16*13+f17
#define R_T7   1717   // 169: (f18,f19)
#define R_T8   1886   // 169: (f20,f21)
#define R_T9   2055   // 13 : f22
#define R_ACT  2068   // 512: actions_emb (bf16)
#define R_BITS 2580   // 5632: 2580 + fi*512 + half*256 + byte
#define NROWS  8212   // total rows (x 512 B = 4,204,544 B)

// k_prep block layout (1024 threads each)
#define B_FUSED  0     // 224 blocks: fused sp/ab/it rows (4 rows, 4-way K-split)
#define B_WBT    224   // 64 blocks : transposed bf16 mlp_w
#define B_BITS   288   // 1408 blocks: bits byte tables (4 rows/block)
#define B_MERGED 1696  // 421 blocks: merged one-hot/boost/action rows (4 rows/block)
#define NB_PREP  2117

#define XP 264         // padded LDS x-row length in ushorts (528 B)

__device__ __forceinline__ unsigned short f2bf(float f) {
    unsigned int u = __float_as_uint(f);
    u += 0x7fffu + ((u >> 16) & 1u);   // round-to-nearest-even
    return (unsigned short)(u >> 16);
}

// ---------------------------------------------------------------------------
// K0: table prep (fused rows / wbt / bits tables / merged rows)
// ---------------------------------------------------------------------------
__global__ __launch_bounds__(1024) void k_prep(
    const float* __restrict__ sp_tbl, const float* __restrict__ ab_tbl,
    const float* __restrict__ it_tbl, const float* __restrict__ sp_emb,
    const float* __restrict__ ab_emb, const float* __restrict__ it_emb,
    const float* __restrict__ act_emb, const float* __restrict__ agg_w,
    const float* __restrict__ agg_b,  const float* __restrict__ mlp_w,
    unsigned short* __restrict__ tbl, unsigned short* __restrict__ wbt)
{
    __shared__ float rowbuf[4 * 512];
    __shared__ float part[4][4][256];
    int blk = blockIdx.x, t = threadIdx.x, c = t & 255;
#define W(x) agg_w[(size_t)(x) * 256 + c]

    if (blk < B_WBT) {
        // ---- fused species/ability/item rows: 4 rows/block, K split 4 ways ----
        int r0 = blk << 2;
        const float* src; const float* emb; int len, wbase; bool add_b;
        if (r0 < 512)      { src = sp_tbl + (size_t)r0 * 512;           emb = sp_emb + (size_t)r0 * 256;           len = 512; wbase = 0;   add_b = true;  }
        else if (r0 < 640) { int q = r0 - 512; src = ab_tbl + (size_t)q * 128; emb = ab_emb + (size_t)q * 256; len = 128; wbase = 512; add_b = false; }
        else               { int q = r0 - 640; src = it_tbl + (size_t)q * 256; emb = it_emb + (size_t)q * 256; len = 256; wbase = 640; add_b = false; }
        int tot = len << 2;
        for (int i = t; i < tot; i += 1024) rowbuf[i] = src[i];
        __syncthreads();
        int kq   = t >> 8;
        int len4 = len >> 2;
        int kbeg = kq * len4, kend = kbeg + len4;
        float a0 = 0.f, a1 = 0.f, a2 = 0.f, a3 = 0.f;
        #pragma unroll 4
        for (int k = kbeg; k < kend; ++k) {
            float w = W(wbase + k);
            a0 += rowbuf[k] * w;
            a1 += rowbuf[len + k] * w;
            a2 += rowbuf[2 * len + k] * w;
            a3 += rowbuf[3 * len + k] * w;
        }
        part[0][kq][c] = a0; part[1][kq][c] = a1;
        part[2][kq][c] = a2; part[3][kq][c] = a3;
        __syncthreads();
        int row = t >> 8;
        float s = part[row][0][c] + part[row][1][c] + part[row][2][c] + part[row][3][c]
                + emb[row * 256 + c] + (add_b ? agg_b[c] : 0.f);
        tbl[(size_t)(r0 + row) * 256 + c] = f2bf(s);
        return;
    }
    if (blk < B_BITS) {
        // ---- transposed bf16 mlp_w ----
        int idx = ((blk - B_WBT) << 10) + t;
        int col = idx >> 8, k = idx & 255;
        wbt[(size_t)col * 256 + k] = f2bf(mlp_w[(size_t)k * 256 + col]);
        return;
    }
    if (blk < B_MERGED) {
        // ---- bits byte tables: 4 rows per block ----
        int idx = ((blk - B_BITS) << 10) + t;
        int row = idx >> 8;                 // 0..5631 = tseg*256 + byte
        int tseg = row >> 8, byte = row & 255;
        int base = 1171 + 16 * (tseg >> 1) + 8 * (tseg & 1);
        float acc = 0.f;
        #pragma unroll
        for (int j = 0; j < 8; ++j)
            if ((byte >> j) & 1) acc += W(base + j);
        tbl[(size_t)(R_BITS + row) * 256 + c] = f2bf(acc);
        return;
    }
    {
        // ---- merged category rows: 4 rows per block ----
        int r = ((blk - B_MERGED) << 2) + (t >> 8);   // 0..1683
        int row; float acc;
        if (r < 404)       { int f3 = r >> 2, f4 = (r >> 1) & 1, f5 = r & 1;
                             acc = W(896 + f3) + W(997 + f4) + W(999 + f5); row = R_T1 + r; }
        else if (r < 532)  { int i = r - 404; int f6 = i >> 2, f11 = (i >> 1) & 1, f12 = i & 1;
                             acc = W(1001 + f6) + (float)f6 * (1.f / 31.f) * W(1347)
                                 + W(1062 + f11) + W(1064 + f12); row = R_T2 + i; }
        else if (r < 556)  { int i = r - 532; acc = W(1033 + (i >> 3)) + W(1036 + (i & 7)); row = R_T3 + i; }
        else if (r < 588)  { int i = r - 556; acc = W(1044 + (i >> 1)) + W(1060 + (i & 1)); row = R_T4 + i; }
        else if (r < 652)  { int i = r - 588; acc = W(1066 + (i >> 3)) + W(1074 + ((i >> 1) & 3)) + W(1078 + (i & 1)); row = R_T5 + i; }
        else if (r < 821)  { int i = r - 652; acc = W(1080 + i / 13) + W(1093 + i % 13); row = R_T6 + i; }
        else if (r < 990)  { int i = r - 821; acc = W(1106 + i / 13) + W(1119 + i % 13); row = R_T7 + i; }
        else if (r < 1159) { int i = r - 990; acc = W(1132 + i / 13) + W(1145 + i % 13); row = R_T8 + i; }
        else if (r < 1172) { int i = r - 1159; acc = W(1158 + i); row = R_T9 + i; }
        else               { int i = r - 1172; acc = act_emb[(size_t)i * 256 + c]; row = R_ACT + i; }
        tbl[(size_t)row * 256 + c] = f2bf(acc);
    }
#undef W
}

// ---------------------------------------------------------------------------
// K1: per-entity packed row indices.  Entity row (152 B) loaded via 10
// aligned dwordx4 covering a 160 B window (e*152 is 8B-aligned; off = 0 or 2
// ints, handled with static-index branches).
// ---------------------------------------------------------------------------
__global__ __launch_bounds__(256) void k_idx(
    const int* __restrict__ ent, unsigned short* __restrict__ ridx)
{
    int e = blockIdx.x * 256 + threadIdx.x;
    size_t bb = (size_t)e * (NFEAT * 4);
    const uint4* wp = reinterpret_cast<const uint4*>(
        reinterpret_cast<const char*>(ent) + (bb & ~(size_t)15));
    uint4 q0 = wp[0], q1 = wp[1], q2 = wp[2], q3 = wp[3], q4 = wp[4];
    uint4 q5 = wp[5], q6 = wp[6], q7 = wp[7], q8 = wp[8], q9 = wp[9];
    unsigned int v[40] = {q0.x,q0.y,q0.z,q0.w, q1.x,q1.y,q1.z,q1.w,
                          q2.x,q2.y,q2.z,q2.w, q3.x,q3.y,q3.z,q3.w,
                          q4.x,q4.y,q4.z,q4.w, q5.x,q5.y,q5.z,q5.w,
                          q6.x,q6.y,q6.z,q6.w, q7.x,q7.y,q7.z,q7.w,
                          q8.x,q8.y,q8.z,q8.w, q9.x,q9.y,q9.z,q9.w};
    int f[NFEAT];
    if (e & 1) {
        #pragma unroll
        for (int i = 0; i < NFEAT; ++i) f[i] = (int)v[i + 2];
    } else {
        #pragma unroll
        for (int i = 0; i < NFEAT; ++i) f[i] = (int)v[i];
    }
    unsigned short r[40];
    r[0] = (unsigned short)f[0];
    r[1] = (unsigned short)(R_AB + f[1]);
    r[2] = (unsigned short)(R_IT + f[2]);
    r[3] = (unsigned short)(R_T1 + f[3] * 4 + f[4] * 2 + f[5]);
    r[4] = (unsigned short)(R_T2 + f[6] * 4 + f[11] * 2 + f[12]);
    r[5] = (unsigned short)(R_T3 + f[7] * 8 + f[8]);
    r[6] = (unsigned short)(R_T4 + f[9] * 2 + f[10]);
    r[7] = (unsigned short)(R_T5 + f[13] * 8 + f[14] * 2 + f[15]);
    r[8] = (unsigned short)(R_T6 + f[16] * 13 + f[17]);
    r[9] = (unsigned short)(R_T7 + f[18] * 13 + f[19]);
    r[10] = (unsigned short)(R_T8 + f[20] * 13 + f[21]);
    r[11] = (unsigned short)(R_T9 + f[22]);
    #pragma unroll
    for (int i = 0; i < 11; ++i) {
        int b = f[23 + i];
        r[12 + 2 * i] = (unsigned short)(R_BITS + i * 512 + (b & 255));
        r[13 + 2 * i] = (unsigned short)(R_BITS + i * 512 + 256 + ((b >> 8) & 255));
    }
    #pragma unroll
    for (int i = 0; i < 4; ++i) r[34 + i] = (unsigned short)(R_ACT + f[34 + i]);
    r[38] = 0; r[39] = 0;
    unsigned int p[20];
    #pragma unroll
    for (int i = 0; i < 20; ++i)
        p[i] = (unsigned int)r[2 * i] | ((unsigned int)r[2 * i + 1] << 16);
    uint4* dst = reinterpret_cast<uint4*>(ridx + (size_t)e * 40);
    dst[0] = make_uint4(p[0], p[1], p[2], p[3]);
    dst[1] = make_uint4(p[4], p[5], p[6], p[7]);
    dst[2] = make_uint4(p[8], p[9], p[10], p[11]);
    dst[3] = make_uint4(p[12], p[13], p[14], p[15]);
    dst[4] = make_uint4(p[16], p[17], p[18], p[19]);
}

// ---------------------------------------------------------------------------
// K2: fused encode + mlp.  Block = 512 threads (8 waves), 64 entities.
// Phase A: wave w gather-encodes entities w*8..w*8+7 -> bf16 rows in LDS
//          (row stride 528 B -> 2-way bank pattern on b128 reads = free).
// Phase B: wave w computes all 64 rows x cols [w*32, w*32+32) via MFMA
//          16x16x32 (A from LDS, B from L2-hot wbt), bias + species mask.
// ---------------------------------------------------------------------------
__global__ __launch_bounds__(512) void k_fused_em(
    const unsigned short* __restrict__ ridx, const unsigned short* __restrict__ tbl,
    const unsigned short* __restrict__ wbt,  const float* __restrict__ mlp_b,
    float* __restrict__ out)
{
    __shared__ unsigned short xlds[64 * XP];   // 33,792 B
    __shared__ unsigned char  smask[64];
    int t    = threadIdx.x;
    int w    = t >> 6;
    int lane = t & 63;
    int half = lane >> 5;
    int cp   = lane & 31;
    int cb   = cp << 4;
    int sh   = half << 4;
    int e0   = blockIdx.x << 6;
    const char* tb = reinterpret_cast<const char*>(tbl);

    // ---------------- phase A: encode 8 entities per wave ----------------
    for (int i = 0; i < 8; ++i) {
        int el = (w << 3) + i;
        int eg = e0 + el;
        const uint4* rp = reinterpret_cast<const uint4*>(ridx + (size_t)eg * 40);
        uint4 r0 = rp[0], r1 = rp[1], r2 = rp[2], r3 = rp[3], r4 = rp[4];
        unsigned int idx32[19] = {r0.x, r0.y, r0.z, r0.w, r1.x, r1.y, r1.z, r1.w,
                                  r2.x, r2.y, r2.z, r2.w, r3.x, r3.y, r3.z, r3.w,
                                  r4.x, r4.y, r4.z};
        float acc[8] = {0.f, 0.f, 0.f, 0.f, 0.f, 0.f, 0.f, 0.f};
        #pragma unroll
        for (int j = 0; j < 19; ++j) {
            unsigned int row = (idx32[j] >> sh) & 0xffffu;
            uint4 v = *reinterpret_cast<const uint4*>(tb + ((size_t)row << 9) + cb);
            acc[0] += __uint_as_float(v.x << 16);
            acc[1] += __uint_as_float(v.x & 0xffff0000u);
            acc[2] += __uint_as_float(v.y << 16);
            acc[3] += __uint_as_float(v.y & 0xffff0000u);
            acc[4] += __uint_as_float(v.z << 16);
            acc[5] += __uint_as_float(v.z & 0xffff0000u);
            acc[6] += __uint_as_float(v.w << 16);
            acc[7] += __uint_as_float(v.w & 0xffff0000u);
        }
        #pragma unroll
        for (int j = 0; j < 8; ++j) acc[j] += __shfl_xor(acc[j], 32);
        if (lane == 0) smask[el] = ((r0.x & 0xffffu) < 2u) ? 1 : 0;
        if (half == 0) {
            unsigned int o0 = (unsigned)f2bf(fmaxf(acc[0], 0.f)) | ((unsigned)f2bf(fmaxf(acc[1], 0.f)) << 16);
            unsigned int o1 = (unsigned)f2bf(fmaxf(acc[2], 0.f)) | ((unsigned)f2bf(fmaxf(acc[3], 0.f)) << 16);
            unsigned int o2 = (unsigned)f2bf(fmaxf(acc[4], 0.f)) | ((unsigned)f2bf(fmaxf(acc[5], 0.f)) << 16);
            unsigned int o3 = (unsigned)f2bf(fmaxf(acc[6], 0.f)) | ((unsigned)f2bf(fmaxf(acc[7], 0.f)) << 16);
            *reinterpret_cast<uint4*>(&xlds[el * XP + (cp << 3)]) = make_uint4(o0, o1, o2, o3);
        }
    }
    __syncthreads();

    // ---------------- phase B: MFMA 64 rows x 32 cols per wave ----------------
    int rc = lane & 15;
    int kg = lane >> 4;
    int c0 = w << 5;

    f32x4 acc0[4], acc1[4];
    #pragma unroll
    for (int mt = 0; mt < 4; ++mt) {
        acc0[mt] = (f32x4){0.f, 0.f, 0.f, 0.f};
        acc1[mt] = (f32x4){0.f, 0.f, 0.f, 0.f};
    }

    #pragma unroll
    for (int k0 = 0; k0 < 256; k0 += 32) {
        bf16x8 b0 = *reinterpret_cast<const bf16x8*>(wbt + (size_t)(c0 + rc) * 256 + k0 + kg * 8);
        bf16x8 b1 = *reinterpret_cast<const bf16x8*>(wbt + (size_t)(c0 + 16 + rc) * 256 + k0 + kg * 8);
        #pragma unroll
        for (int mt = 0; mt < 4; ++mt) {
            bf16x8 a = *reinterpret_cast<const bf16x8*>(&xlds[(mt * 16 + rc) * XP + k0 + kg * 8]);
            acc0[mt] = __builtin_amdgcn_mfma_f32_16x16x32_bf16(a, b0, acc0[mt], 0, 0, 0);
            acc1[mt] = __builtin_amdgcn_mfma_f32_16x16x32_bf16(a, b1, acc1[mt], 0, 0, 0);
        }
    }

    float bias0 = mlp_b[c0 + rc];
    float bias1 = mlp_b[c0 + 16 + rc];
    #pragma unroll
    for (int mt = 0; mt < 4; ++mt) {
        unsigned int mw = *reinterpret_cast<const unsigned int*>(&smask[mt * 16 + kg * 4]);
        #pragma unroll
        for (int r = 0; r < 4; ++r) {
            int row = e0 + mt * 16 + kg * 4 + r;
            bool msk = (mw >> (8 * r)) & 1u;
            float v0 = acc0[mt][r] + bias0;
            float v1 = acc1[mt][r] + bias1;
            out[(size_t)row * 256 + c0 + rc]      = msk ? 0.f : v0;
            out[(size_t)row * 256 + c0 + 16 + rc] = msk ? 0.f : v1;
        }
    }
}

// ---------------------------------------------------------------------------
extern "C" void kernel_launch(void* const* d_in, const int* in_sizes, int n_in,
                              void* d_out, int out_size, void* d_ws, size_t ws_size,
                              hipStream_t stream)
{
    const int*   ent     = (const int*)d_in[0];
    const float* sp_tbl  = (const float*)d_in[1];
    const float* ab_tbl  = (const float*)d_in[2];
    const float* it_tbl  = (const float*)d_in[3];
    const float* sp_emb  = (const float*)d_in[4];
    const float* ab_emb  = (const float*)d_in[5];
    const float* it_emb  = (const float*)d_in[6];
    const float* act_emb = (const float*)d_in[7];
    const float* agg_w   = (const float*)d_in[8];
    const float* agg_b   = (const float*)d_in[9];
    const float* mlp_w   = (const float*)d_in[10];
    const float* mlp_b   = (const float*)d_in[11];
    float* out = (float*)d_out;

    char* ws = (char*)d_ws;
    unsigned short* tbl  = (unsigned short*)(ws);                // 8212*512 = 4,204,544 B
    unsigned short* wbt  = (unsigned short*)(ws + 4204544);      //   131,072 B
    unsigned short* ridx = (unsigned short*)(ws + 4335616);      // 65536*80 = 5,242,880 B

    k_prep    <<<dim3(NB_PREP), dim3(1024), 0, stream>>>(sp_tbl, ab_tbl, it_tbl,
                                                         sp_emb, ab_emb, it_emb,
                                                         act_emb, agg_w, agg_b, mlp_w,
                                                         tbl, wbt);
    k_idx     <<<dim3(256),     dim3(256),  0, stream>>>(ent, ridx);
    k_fused_em<<<dim3(1024),    dim3(512),  0, stream>>>(ridx, tbl, wbt, mlp_b, out);
}